// Round 1
// baseline (508.599 us; speedup 1.0000x reference)
//
#include <hip/hip_runtime.h>

typedef short short8 __attribute__((ext_vector_type(8)));
typedef float floatx4 __attribute__((ext_vector_type(4)));
typedef unsigned short ushort_t;

constexpr int Bn = 128, Tn = 2048, DPn = 256, DQn = 256, DOn = 256;

__device__ inline unsigned short f2bf(float x) {
    unsigned u = __float_as_uint(x);
    u += 0x7fffu + ((u >> 16) & 1u);   // RNE
    return (unsigned short)(u >> 16);
}

__device__ inline float fast_tanh(float x) {
    // 1 - 2/(e^{2x}+1); safe at +-inf (overflow -> 1, underflow -> -1)
    float e = __expf(2.0f * x);
    return 1.0f - 2.0f / (e + 1.0f);
}

// ---------------- Kernel 0: W_q (fp32 [DO,DQ]) -> bf16 ----------------
__global__ __launch_bounds__(256) void cvt_wq_kernel(const float* __restrict__ wq,
                                                     unsigned short* __restrict__ wqbf) {
    int idx = blockIdx.x * 256 + threadIdx.x;       // 16384 threads, 4 elems each
    float4 v = ((const float4*)wq)[idx];
    unsigned p0 = (unsigned)f2bf(v.x) | ((unsigned)f2bf(v.y) << 16);
    unsigned p1 = (unsigned)f2bf(v.z) | ((unsigned)f2bf(v.w) << 16);
    ((uint2*)wqbf)[idx] = make_uint2(p0, p1);
}

// ---------------- Kernel 1: base[b][d] = W_p_r[d]·[input_p[b],h[b]] + b_p_r[d] + b_q[d] ----------------
__global__ __launch_bounds__(256) void base_kernel(const float* __restrict__ input_p,
                                                   const float* __restrict__ h_tm1,
                                                   const float* __restrict__ Wpr,
                                                   const float* __restrict__ bpr,
                                                   const float* __restrict__ bq,
                                                   float* __restrict__ base) {
    __shared__ float v[512];
    int b = blockIdx.x, tid = threadIdx.x;
    v[tid]       = input_p[b * DPn + tid];
    v[256 + tid] = h_tm1[b * DOn + tid];
    __syncthreads();
    const float4* row = (const float4*)(Wpr + (size_t)tid * 512);
    const float4* vv  = (const float4*)v;
    float acc = 0.f;
#pragma unroll 8
    for (int i = 0; i < 128; i++) {
        float4 r = row[i], x = vv[i];
        acc = fmaf(r.x, x.x, acc);
        acc = fmaf(r.y, x.y, acc);
        acc = fmaf(r.z, x.z, acc);
        acc = fmaf(r.w, x.w, acc);
    }
    base[b * DOn + tid] = acc + bpr[tid] + bq[tid];
}

// ---------------- Kernel 2: logits[b][t] = w · tanh(base[b] + W_q q[b,t]) + match_b ----------------
// grid (T/64, B), 256 threads (4 waves). Wave w covers n in [w*64, w*64+64).
__global__ __launch_bounds__(256) void logits_kernel(const float* __restrict__ q,
                                                     const unsigned short* __restrict__ wqbf,
                                                     const float* __restrict__ base,
                                                     const float* __restrict__ wvec,
                                                     const float* __restrict__ matchb,
                                                     float* __restrict__ alpha) {
    __shared__ unsigned short qtile[64 * 264];   // +8 pad: bank-conflict-free ds_read_b128
    __shared__ float basel[256];
    __shared__ float wl[256];
    __shared__ float partl[4][64];

    int b = blockIdx.y;
    int t0 = blockIdx.x * 64;
    int tid = threadIdx.x;

    // stage q tile (64 rows x 256 k) as bf16 into LDS
    {
        int r = tid >> 2;
        int kb = (tid & 3) * 64;
        const float* src = q + ((size_t)b * Tn + t0 + r) * DQn + kb;
        unsigned short* dst = qtile + r * 264 + kb;
#pragma unroll
        for (int i = 0; i < 16; i++) {
            float4 v = *(const float4*)(src + i * 4);
            unsigned p0 = (unsigned)f2bf(v.x) | ((unsigned)f2bf(v.y) << 16);
            unsigned p1 = (unsigned)f2bf(v.z) | ((unsigned)f2bf(v.w) << 16);
            *(uint2*)(dst + i * 4) = make_uint2(p0, p1);
        }
    }
    basel[tid] = base[b * DOn + tid];
    wl[tid] = wvec[tid];
    __syncthreads();

    int w = tid >> 6, lane = tid & 63, quad = lane >> 4, l15 = lane & 15;
    float p[4][4] = {{0.f}};
    int n0w = w * 64;

#pragma unroll
    for (int nt = 0; nt < 4; nt++) {
        int nn = n0w + nt * 16 + l15;                 // output col (d index)
        short8 bfrag[8];
        const unsigned short* bp = wqbf + (size_t)nn * DQn + quad * 8;
#pragma unroll
        for (int ks = 0; ks < 8; ks++) bfrag[ks] = *(const short8*)(bp + ks * 32);
        float bn = basel[nn], wn = wl[nn];
#pragma unroll
        for (int mt = 0; mt < 4; mt++) {
            const unsigned short* ap = qtile + (mt * 16 + l15) * 264 + quad * 8;
            floatx4 acc = {0.f, 0.f, 0.f, 0.f};
#pragma unroll
            for (int ks = 0; ks < 8; ks++) {
                short8 af = *(const short8*)(ap + ks * 32);
                acc = __builtin_amdgcn_mfma_f32_16x16x32_bf16(af, bfrag[ks], acc, 0, 0, 0);
            }
            // C layout: row = quad*4 + r (within mtile), col = l15
#pragma unroll
            for (int r = 0; r < 4; r++) {
                float g = fast_tanh(acc[r] + bn);
                p[mt][r] = fmaf(g, wn, p[mt][r]);
            }
        }
    }
    // reduce across the 16 col-lanes (l15 dimension)
#pragma unroll
    for (int off = 1; off < 16; off <<= 1) {
#pragma unroll
        for (int mt = 0; mt < 4; mt++)
#pragma unroll
            for (int r = 0; r < 4; r++) p[mt][r] += __shfl_xor(p[mt][r], off);
    }
    if (l15 == 0) {
#pragma unroll
        for (int mt = 0; mt < 4; mt++)
#pragma unroll
            for (int r = 0; r < 4; r++) partl[w][mt * 16 + quad * 4 + r] = p[mt][r];
    }
    __syncthreads();
    if (tid < 64) {
        float lg = partl[0][tid] + partl[1][tid] + partl[2][tid] + partl[3][tid] + matchb[0];
        alpha[(size_t)b * Tn + t0 + tid] = lg;
    }
}

// ---------------- Kernel 3: masked softmax over T, in place ----------------
__global__ __launch_bounds__(256) void softmax_kernel(float* __restrict__ alpha,
                                                      const int* __restrict__ maskq) {
    __shared__ float redmax[4];
    __shared__ float redsum[4];
    int b = blockIdx.x, tid = threadIdx.x;
    int lane = tid & 63, w = tid >> 6;
    float x[8], mv[8];
    float lmax = -1e30f;
#pragma unroll
    for (int i = 0; i < 8; i++) {
        int t = tid + i * 256;
        float a = alpha[(size_t)b * Tn + t];
        float mi = (float)maskq[(size_t)b * Tn + t];
        float xi = fminf(fmaxf(a, -15.f), 15.f) * mi;   // clip then mask (ref order)
        x[i] = xi;
        mv[i] = mi;
        lmax = fmaxf(lmax, xi);
    }
#pragma unroll
    for (int off = 32; off >= 1; off >>= 1) lmax = fmaxf(lmax, __shfl_xor(lmax, off));
    if (lane == 0) redmax[w] = lmax;
    __syncthreads();
    float mx = fmaxf(fmaxf(redmax[0], redmax[1]), fmaxf(redmax[2], redmax[3]));

    float e[8];
    float lsum = 0.f;
#pragma unroll
    for (int i = 0; i < 8; i++) {
        e[i] = __expf(x[i] - mx) * mv[i];
        lsum += e[i];
    }
#pragma unroll
    for (int off = 32; off >= 1; off >>= 1) lsum += __shfl_xor(lsum, off);
    if (lane == 0) redsum[w] = lsum;
    __syncthreads();
    float s = redsum[0] + redsum[1] + redsum[2] + redsum[3];
    float inv = 1.0f / (s + 1e-6f);
#pragma unroll
    for (int i = 0; i < 8; i++) alpha[(size_t)b * Tn + tid + i * 256] = e[i] * inv;
}

// ---------------- Kernel 4: partial z over t-chunks ----------------
// grid (16, B): chunk c covers t in [c*128, c*128+128); thread = d
__global__ __launch_bounds__(256) void zpart_kernel(const float* __restrict__ q,
                                                    const float* __restrict__ alpha,
                                                    float* __restrict__ zpart) {
    int b = blockIdx.y, c = blockIdx.x, tid = threadIdx.x;
    int t0 = c * 128;
    const float* qp = q + ((size_t)b * Tn + t0) * DQn + tid;
    const float* ap = alpha + (size_t)b * Tn + t0;
    float acc = 0.f;
#pragma unroll 4
    for (int t = 0; t < 128; t++) acc = fmaf(ap[t], qp[(size_t)t * DQn], acc);
    zpart[((size_t)b * 16 + c) * DQn + tid] = acc;
}

// ---------------- Kernel 5: out = [input_p | z] ----------------
__global__ __launch_bounds__(256) void finalize_kernel(const float* __restrict__ input_p,
                                                       const float* __restrict__ zpart,
                                                       float* __restrict__ out) {
    int b = blockIdx.x, tid = threadIdx.x;
    out[(size_t)b * 512 + tid] = input_p[(size_t)b * DPn + tid];
    float z = 0.f;
#pragma unroll
    for (int c = 0; c < 16; c++) z += zpart[((size_t)b * 16 + c) * DQn + tid];
    out[(size_t)b * 512 + 256 + tid] = z;
}

extern "C" void kernel_launch(void* const* d_in, const int* in_sizes, int n_in,
                              void* d_out, int out_size, void* d_ws, size_t ws_size,
                              hipStream_t stream) {
    const float* input_p = (const float*)d_in[0];
    // d_in[1] = mask_p (unused by reference)
    const float* input_q = (const float*)d_in[2];
    const int*   mask_q  = (const int*)d_in[3];
    const float* h_tm1   = (const float*)d_in[4];
    const float* W_p_r   = (const float*)d_in[5];
    const float* b_p_r   = (const float*)d_in[6];
    const float* W_q     = (const float*)d_in[7];
    const float* b_q     = (const float*)d_in[8];
    const float* w       = (const float*)d_in[9];
    const float* match_b = (const float*)d_in[10];
    // d_in[11] = depth (unused, layer 0)
    float* out = (float*)d_out;

    char* ws = (char*)d_ws;
    unsigned short* wqbf = (unsigned short*)ws;               // 256*256*2   = 131072 B
    float* base  = (float*)(ws + 131072);                     // 128*256*4   = 131072 B
    float* alpha = (float*)(ws + 262144);                     // 128*2048*4  = 1 MiB
    float* zpart = (float*)(ws + 262144 + 1048576);           // 128*16*256*4 = 2 MiB

    cvt_wq_kernel<<<64, 256, 0, stream>>>(W_q, wqbf);
    base_kernel<<<Bn, 256, 0, stream>>>(input_p, h_tm1, W_p_r, b_p_r, b_q, base);
    logits_kernel<<<dim3(Tn / 64, Bn), 256, 0, stream>>>(input_q, wqbf, base, w, match_b, alpha);
    softmax_kernel<<<Bn, 256, 0, stream>>>(alpha, mask_q);
    zpart_kernel<<<dim3(16, Bn), 256, 0, stream>>>(input_q, alpha, zpart);
    finalize_kernel<<<Bn, 256, 0, stream>>>(input_p, zpart, out);
}

// Round 2
// 452.022 us; speedup vs baseline: 1.1252x; 1.1252x over previous
//
#include <hip/hip_runtime.h>

typedef short short8 __attribute__((ext_vector_type(8)));
typedef float floatx4 __attribute__((ext_vector_type(4)));

constexpr int Bn = 128, Tn = 2048, DPn = 256, DQn = 256, DOn = 256;
constexpr int NCH = Tn / 64;   // 32 t-chunks of 64 per batch row

__device__ inline unsigned short f2bf(float x) {
    unsigned u = __float_as_uint(x);
    u += 0x7fffu + ((u >> 16) & 1u);   // RNE
    return (unsigned short)(u >> 16);
}
__device__ inline float bf2f(unsigned short h) {
    return __uint_as_float(((unsigned)h) << 16);
}
__device__ inline float fast_tanh(float x) {
    float e = __expf(2.0f * x);
    return 1.0f - 2.0f / (e + 1.0f);
}

// ---------------- Kernel 0: W_q (fp32 [DO,DQ]) -> bf16 ----------------
__global__ __launch_bounds__(256) void cvt_wq_kernel(const float* __restrict__ wq,
                                                     unsigned short* __restrict__ wqbf) {
    int idx = blockIdx.x * 256 + threadIdx.x;
    float4 v = ((const float4*)wq)[idx];
    unsigned p0 = (unsigned)f2bf(v.x) | ((unsigned)f2bf(v.y) << 16);
    unsigned p1 = (unsigned)f2bf(v.z) | ((unsigned)f2bf(v.w) << 16);
    ((uint2*)wqbf)[idx] = make_uint2(p0, p1);
}

// ---------------- Kernel 1: base[b][d] = W_p_r[d]·[input_p[b],h[b]] + b_p_r[d] + b_q[d] ----------------
__global__ __launch_bounds__(256) void base_kernel(const float* __restrict__ input_p,
                                                   const float* __restrict__ h_tm1,
                                                   const float* __restrict__ Wpr,
                                                   const float* __restrict__ bpr,
                                                   const float* __restrict__ bq,
                                                   float* __restrict__ base) {
    __shared__ float v[512];
    int b = blockIdx.x, tid = threadIdx.x;
    v[tid]       = input_p[b * DPn + tid];
    v[256 + tid] = h_tm1[b * DOn + tid];
    __syncthreads();
    const float4* row = (const float4*)(Wpr + (size_t)tid * 512);
    const float4* vv  = (const float4*)v;
    float acc = 0.f;
#pragma unroll 8
    for (int i = 0; i < 128; i++) {
        float4 r = row[i], x = vv[i];
        acc = fmaf(r.x, x.x, acc);
        acc = fmaf(r.y, x.y, acc);
        acc = fmaf(r.z, x.z, acc);
        acc = fmaf(r.w, x.w, acc);
    }
    base[b * DOn + tid] = acc + bpr[tid] + bq[tid];
}

// ---------------- Kernel 2 (fused): logits -> e' = exp(clip(lg)*m - 15)*m -> znum partials ----------------
// grid (32, 128): block = (b, t-chunk of 64). 256 threads = 4 waves.
// LDS q-tile in FRAGMENT-CONTIGUOUS layout: panel p=(mt*8+ks), slot=lane:
//   qtile[(p*64 + lane)*8 + j] = bf16 q[t0 + mt*16 + (lane&15)][ks*32 + (lane>>4)*8 + j]
// -> every ds_write_b128 / ds_read_b128 is a contiguous 1 KB panel (conflict-free).
// W_q bf16 fragments live in 128 VGPRs for the whole block (loaded once from L2).
__global__ __launch_bounds__(256, 2) void fused_kernel(const float* __restrict__ q,
                                                       const unsigned short* __restrict__ wqbf,
                                                       const float* __restrict__ base,
                                                       const float* __restrict__ wvec,
                                                       const float* __restrict__ matchb,
                                                       const int* __restrict__ maskq,
                                                       float* __restrict__ zpart,
                                                       float* __restrict__ spart,
                                                       float* __restrict__ mpart) {
    __shared__ unsigned short qtile[32 * 64 * 8];   // 32 KB
    __shared__ float partl[4][64];
    __shared__ float earr[64];
    __shared__ float zp[4][256];

    int b = blockIdx.y, c = blockIdx.x;
    int t0 = c * 64;
    int tid = threadIdx.x;
    int w = tid >> 6, lane = tid & 63, l15 = lane & 15, quad = lane >> 4;

    // ---- B fragments (held in registers all block) + per-n scalars ----
    short8 bfr[4][8];
    const unsigned short* bbase = wqbf + (size_t)(w * 64 + l15) * 256 + quad * 8;
#pragma unroll
    for (int nt = 0; nt < 4; nt++)
#pragma unroll
        for (int ks = 0; ks < 8; ks++)
            bfr[nt][ks] = *(const short8*)(bbase + nt * 16 * 256 + ks * 32);
    float bn[4], wn[4];
#pragma unroll
    for (int nt = 0; nt < 4; nt++) {
        int n = w * 64 + nt * 16 + l15;
        bn[nt] = base[b * DOn + n];
        wn[nt] = wvec[n];
    }

    // ---- stage q tile: wave w loads rows [w*16, w*16+16), writes panels (w, ks) ----
    {
        const float* src = q + ((size_t)b * Tn + t0 + w * 16 + l15) * DQn + quad * 8;
        unsigned short* dst = qtile + ((size_t)(w * 8) * 64 + lane) * 8;
#pragma unroll
        for (int ks = 0; ks < 8; ks++) {
            float4 v0 = *(const float4*)(src + ks * 32);
            float4 v1 = *(const float4*)(src + ks * 32 + 4);
            short8 s;
            s[0] = (short)f2bf(v0.x); s[1] = (short)f2bf(v0.y);
            s[2] = (short)f2bf(v0.z); s[3] = (short)f2bf(v0.w);
            s[4] = (short)f2bf(v1.x); s[5] = (short)f2bf(v1.y);
            s[6] = (short)f2bf(v1.z); s[7] = (short)f2bf(v1.w);
            *(short8*)(dst + ks * 512) = s;
        }
    }
    __syncthreads();

    // ---- logits: mt outer (A-frags loaded once), nt inner (B from regs) ----
#pragma unroll
    for (int mt = 0; mt < 4; mt++) {
        short8 af[8];
        const unsigned short* ab = qtile + ((size_t)(mt * 8) * 64 + lane) * 8;
#pragma unroll
        for (int ks = 0; ks < 8; ks++) af[ks] = *(const short8*)(ab + ks * 512);
        float prow[4] = {0.f, 0.f, 0.f, 0.f};
#pragma unroll
        for (int nt = 0; nt < 4; nt++) {
            floatx4 acc = {0.f, 0.f, 0.f, 0.f};
#pragma unroll
            for (int ks = 0; ks < 8; ks++)
                acc = __builtin_amdgcn_mfma_f32_16x16x32_bf16(af[ks], bfr[nt][ks], acc, 0, 0, 0);
#pragma unroll
            for (int r = 0; r < 4; r++) {
                float g = fast_tanh(acc[r] + bn[nt]);
                prow[r] = fmaf(g, wn[nt], prow[r]);
            }
        }
        // reduce partial logits over the 16 col-lanes (l15)
#pragma unroll
        for (int off = 1; off < 16; off <<= 1)
#pragma unroll
            for (int r = 0; r < 4; r++) prow[r] += __shfl_xor(prow[r], off);
        if (l15 == 0) {
#pragma unroll
            for (int r = 0; r < 4; r++) partl[w][mt * 16 + quad * 4 + r] = prow[r];
        }
    }
    __syncthreads();

    // ---- e' = exp(clip(lg)*m - 15)*m ; chunk max & sum (exact-softmax bookkeeping) ----
    if (tid < 64) {
        int t = tid;
        float lg = partl[0][t] + partl[1][t] + partl[2][t] + partl[3][t] + matchb[0];
        float m = (float)maskq[(size_t)b * Tn + t0 + t];
        float x = fminf(fmaxf(lg, -15.f), 15.f) * m;
        float e = __expf(x - 15.f) * m;
        earr[t] = e;
        float xm = x, es = e;
#pragma unroll
        for (int off = 1; off < 64; off <<= 1) {
            xm = fmaxf(xm, __shfl_xor(xm, off));
            es += __shfl_xor(es, off);
        }
        if (t == 0) {
            mpart[b * NCH + c] = xm;
            spart[b * NCH + c] = es;
        }
    }
    __syncthreads();

    // ---- znum partial: wave w owns rows t = w*16 + l15; clean panel reads (w, i) ----
    float et = earr[w * 16 + l15];
#pragma unroll
    for (int i = 0; i < 8; i++) {
        short8 f = *(const short8*)(qtile + ((size_t)(w * 8 + i) * 64 + lane) * 8);
        float v[8];
#pragma unroll
        for (int j = 0; j < 8; j++) v[j] = bf2f((unsigned short)f[j]) * et;
        // reduce over the 16 row-lanes (l15)
#pragma unroll
        for (int off = 1; off < 16; off <<= 1)
#pragma unroll
            for (int j = 0; j < 8; j++) v[j] += __shfl_xor(v[j], off);
        if (l15 == 0) {
            float* zd = &zp[w][i * 32 + quad * 8];
            *(float4*)(zd)     = make_float4(v[0], v[1], v[2], v[3]);
            *(float4*)(zd + 4) = make_float4(v[4], v[5], v[6], v[7]);
        }
    }
    __syncthreads();

    // ---- combine 4 wave-partials, write chunk znum ----
    {
        int d = tid;
        float zs = zp[0][d] + zp[1][d] + zp[2][d] + zp[3][d];
        zpart[((size_t)b * NCH + c) * DQn + d] = zs;
    }
}

// ---------------- Kernel 3: exact denom + combine + concat ----------------
// z = (Σ_c znum_c) / (S' + 1e-6 * exp(mx - 15))   — identical to reference softmax math.
__global__ __launch_bounds__(256) void final_kernel(const float* __restrict__ input_p,
                                                    const float* __restrict__ zpart,
                                                    const float* __restrict__ spart,
                                                    const float* __restrict__ mpart,
                                                    float* __restrict__ out) {
    int b = blockIdx.x, tid = threadIdx.x;
    float S = 0.f, mx = -1e30f;
#pragma unroll 8
    for (int c = 0; c < NCH; c++) {
        S += spart[b * NCH + c];
        mx = fmaxf(mx, mpart[b * NCH + c]);
    }
    float denom = S + 1e-6f * __expf(mx - 15.f);
    float inv = 1.0f / denom;
    float zs = 0.f;
#pragma unroll 8
    for (int c = 0; c < NCH; c++) zs += zpart[((size_t)b * NCH + c) * DQn + tid];
    out[(size_t)b * 512 + tid] = input_p[(size_t)b * DPn + tid];
    out[(size_t)b * 512 + 256 + tid] = zs * inv;
}

extern "C" void kernel_launch(void* const* d_in, const int* in_sizes, int n_in,
                              void* d_out, int out_size, void* d_ws, size_t ws_size,
                              hipStream_t stream) {
    const float* input_p = (const float*)d_in[0];
    // d_in[1] = mask_p (unused by reference)
    const float* input_q = (const float*)d_in[2];
    const int*   mask_q  = (const int*)d_in[3];
    const float* h_tm1   = (const float*)d_in[4];
    const float* W_p_r   = (const float*)d_in[5];
    const float* b_p_r   = (const float*)d_in[6];
    const float* W_q     = (const float*)d_in[7];
    const float* b_q     = (const float*)d_in[8];
    const float* w       = (const float*)d_in[9];
    const float* match_b = (const float*)d_in[10];
    // d_in[11] = depth (unused, layer 0)
    float* out = (float*)d_out;

    char* ws = (char*)d_ws;
    unsigned short* wqbf = (unsigned short*)ws;                   // 128 KiB
    float* base  = (float*)(ws + 131072);                         // 128 KiB
    float* zpart = (float*)(ws + 262144);                         // 128*32*256*4 = 4 MiB
    float* spart = (float*)(ws + 262144 + 4194304);               // 16 KiB
    float* mpart = (float*)(ws + 262144 + 4194304 + 16384);       // 16 KiB

    cvt_wq_kernel<<<64, 256, 0, stream>>>(W_q, wqbf);
    base_kernel<<<Bn, 256, 0, stream>>>(input_p, h_tm1, W_p_r, b_p_r, b_q, base);
    fused_kernel<<<dim3(NCH, Bn), 256, 0, stream>>>(input_q, wqbf, base, w, match_b,
                                                    mask_q, zpart, spart, mpart);
    final_kernel<<<Bn, 256, 0, stream>>>(input_p, zpart, spart, mpart, out);
}

// Round 3
// 439.163 us; speedup vs baseline: 1.1581x; 1.0293x over previous
//
#include <hip/hip_runtime.h>
#include <hip/hip_bf16.h>

typedef short short8 __attribute__((ext_vector_type(8)));
typedef float floatx4 __attribute__((ext_vector_type(4)));

constexpr int Bn = 128, Tn = 2048, DPn = 256, DQn = 256, DOn = 256;
constexpr int NCH = Tn / 64;   // 32 t-chunks of 64 per batch row

__device__ inline unsigned pk2(float x, float y) {
    __hip_bfloat162 h = __float22bfloat162_rn(make_float2(x, y));  // v_cvt_pk_bf16_f32
    return *(unsigned*)&h;   // low 16 = x, high 16 = y
}
__device__ inline float fast_tanh(float x) {
    float e = __expf(2.0f * x);
    return 1.0f - 2.0f / (e + 1.0f);
}

// ---------------- Kernel 0: W_q (fp32 [DO,DQ]) -> bf16 ----------------
__global__ __launch_bounds__(256) void cvt_wq_kernel(const float* __restrict__ wq,
                                                     unsigned short* __restrict__ wqbf) {
    int idx = blockIdx.x * 256 + threadIdx.x;
    float4 v = ((const float4*)wq)[idx];
    ((uint2*)wqbf)[idx] = make_uint2(pk2(v.x, v.y), pk2(v.z, v.w));
}

// ---------------- Kernel 1: base[b][d] = W_p_r[d]·[input_p[b],h[b]] + b_p_r[d] + b_q[d] ----------------
__global__ __launch_bounds__(256) void base_kernel(const float* __restrict__ input_p,
                                                   const float* __restrict__ h_tm1,
                                                   const float* __restrict__ Wpr,
                                                   const float* __restrict__ bpr,
                                                   const float* __restrict__ bq,
                                                   float* __restrict__ base) {
    __shared__ float v[512];
    int b = blockIdx.x, tid = threadIdx.x;
    v[tid]       = input_p[b * DPn + tid];
    v[256 + tid] = h_tm1[b * DOn + tid];
    __syncthreads();
    const float4* row = (const float4*)(Wpr + (size_t)tid * 512);
    const float4* vv  = (const float4*)v;
    float acc = 0.f;
#pragma unroll 8
    for (int i = 0; i < 128; i++) {
        float4 r = row[i], x = vv[i];
        acc = fmaf(r.x, x.x, acc);
        acc = fmaf(r.y, x.y, acc);
        acc = fmaf(r.z, x.z, acc);
        acc = fmaf(r.w, x.w, acc);
    }
    base[b * DOn + tid] = acc + bpr[tid] + bq[tid];
}

// ---------------- Kernel 2 (fused): logits -> e' -> znum partials ----------------
// grid (32, 128): block = (b, t-chunk of 64). 256 threads = 4 waves.
// Phase A: stage q-tile bf16 in fragment-contiguous LDS panels, MFMA logits,
//          reduce w·tanh over the 16 col-lanes.
// Phase B: e' = exp(clip(lg)*m - 15)*m, per-chunk max/sum bookkeeping.
// Phase C: znum[d] = sum_t e'_t q[t][d] via DIRECT coalesced global re-read
//          (L1/L2-hot), register accumulate, tiny LDS combine (aliased over
//          the dead q-tile). No shuffle storm on the LDS pipe.
__global__ __launch_bounds__(256, 2) void fused_kernel(const float* __restrict__ q,
                                                       const unsigned short* __restrict__ wqbf,
                                                       const float* __restrict__ base,
                                                       const float* __restrict__ wvec,
                                                       const float* __restrict__ matchb,
                                                       const int* __restrict__ maskq,
                                                       float* __restrict__ zpart,
                                                       float* __restrict__ spart,
                                                       float* __restrict__ mpart) {
    __shared__ __align__(16) char shraw[32 * 64 * 16];   // 32 KB: qtile, later zp
    unsigned short* qtile = (unsigned short*)shraw;
    __shared__ float partl[4][64];
    __shared__ float earr[64];

    int b = blockIdx.y, c = blockIdx.x;
    int t0 = c * 64;
    int tid = threadIdx.x;
    int w = tid >> 6, lane = tid & 63, l15 = lane & 15, quad = lane >> 4;

    // ---- B fragments (registers for whole block) + per-n scalars ----
    short8 bfr[4][8];
    const unsigned short* bbase = wqbf + (size_t)(w * 64 + l15) * 256 + quad * 8;
#pragma unroll
    for (int nt = 0; nt < 4; nt++)
#pragma unroll
        for (int ks = 0; ks < 8; ks++)
            bfr[nt][ks] = *(const short8*)(bbase + nt * 16 * 256 + ks * 32);
    float bn[4], wn[4];
#pragma unroll
    for (int nt = 0; nt < 4; nt++) {
        int n = w * 64 + nt * 16 + l15;
        bn[nt] = base[b * DOn + n];
        wn[nt] = wvec[n];
    }

    // ---- stage q tile (packed bf16 cvt) ----
    {
        const float* src = q + ((size_t)b * Tn + t0 + w * 16 + l15) * DQn + quad * 8;
        unsigned short* dst = qtile + ((size_t)(w * 8) * 64 + lane) * 8;
#pragma unroll
        for (int ks = 0; ks < 8; ks++) {
            float4 v0 = *(const float4*)(src + ks * 32);
            float4 v1 = *(const float4*)(src + ks * 32 + 4);
            uint4 u;
            u.x = pk2(v0.x, v0.y);
            u.y = pk2(v0.z, v0.w);
            u.z = pk2(v1.x, v1.y);
            u.w = pk2(v1.z, v1.w);
            *(uint4*)(dst + ks * 512) = u;
        }
    }
    __syncthreads();

    // ---- logits: mt outer (A-frags loaded once), nt inner (B from regs) ----
#pragma unroll
    for (int mt = 0; mt < 4; mt++) {
        short8 af[8];
        const unsigned short* ab = qtile + ((size_t)(mt * 8) * 64 + lane) * 8;
#pragma unroll
        for (int ks = 0; ks < 8; ks++) af[ks] = *(const short8*)(ab + ks * 512);
        float prow[4] = {0.f, 0.f, 0.f, 0.f};
#pragma unroll
        for (int nt = 0; nt < 4; nt++) {
            floatx4 acc = {0.f, 0.f, 0.f, 0.f};
#pragma unroll
            for (int ks = 0; ks < 8; ks++)
                acc = __builtin_amdgcn_mfma_f32_16x16x32_bf16(af[ks], bfr[nt][ks], acc, 0, 0, 0);
#pragma unroll
            for (int r = 0; r < 4; r++) {
                float g = fast_tanh(acc[r] + bn[nt]);
                prow[r] = fmaf(g, wn[nt], prow[r]);
            }
        }
#pragma unroll
        for (int off = 1; off < 16; off <<= 1)
#pragma unroll
            for (int r = 0; r < 4; r++) prow[r] += __shfl_xor(prow[r], off);
        if (l15 == 0) {
#pragma unroll
            for (int r = 0; r < 4; r++) partl[w][mt * 16 + quad * 4 + r] = prow[r];
        }
    }
    __syncthreads();

    // ---- e' = exp(clip(lg)*m - 15)*m ; chunk max & sum ----
    if (tid < 64) {
        int t = tid;
        float lg = partl[0][t] + partl[1][t] + partl[2][t] + partl[3][t] + matchb[0];
        float m = (float)maskq[(size_t)b * Tn + t0 + t];
        float x = fminf(fmaxf(lg, -15.f), 15.f) * m;
        float e = __expf(x - 15.f) * m;
        earr[t] = e;
        float xm = x, es = e;
#pragma unroll
        for (int off = 1; off < 64; off <<= 1) {
            xm = fmaxf(xm, __shfl_xor(xm, off));
            es += __shfl_xor(es, off);
        }
        if (t == 0) {
            mpart[b * NCH + c] = xm;
            spart[b * NCH + c] = es;
        }
    }
    __syncthreads();

    // ---- znum: lane owns d-octet o and t-group g; coalesced global re-read ----
    {
        int o = lane & 31, h = lane >> 5, g = w * 2 + h;
        const float* qz = q + ((size_t)b * Tn + t0 + g * 8) * DQn + o * 8;
        float acc[8] = {0.f, 0.f, 0.f, 0.f, 0.f, 0.f, 0.f, 0.f};
#pragma unroll
        for (int s = 0; s < 8; s++) {
            float e = earr[g * 8 + s];
            float4 a0 = *(const float4*)(qz + (size_t)s * DQn);
            float4 a1 = *(const float4*)(qz + (size_t)s * DQn + 4);
            acc[0] = fmaf(e, a0.x, acc[0]);
            acc[1] = fmaf(e, a0.y, acc[1]);
            acc[2] = fmaf(e, a0.z, acc[2]);
            acc[3] = fmaf(e, a0.w, acc[3]);
            acc[4] = fmaf(e, a1.x, acc[4]);
            acc[5] = fmaf(e, a1.y, acc[5]);
            acc[6] = fmaf(e, a1.z, acc[6]);
            acc[7] = fmaf(e, a1.w, acc[7]);
        }
        float* zp = (float*)shraw;   // alias over dead qtile (8*256 floats = 8 KB)
        float* zrow = zp + g * 256 + o * 8;
        *(float4*)(zrow)     = make_float4(acc[0], acc[1], acc[2], acc[3]);
        *(float4*)(zrow + 4) = make_float4(acc[4], acc[5], acc[6], acc[7]);
    }
    __syncthreads();
    {
        const float* zp = (const float*)shraw;
        float zs = 0.f;
#pragma unroll
        for (int r = 0; r < 8; r++) zs += zp[r * 256 + tid];
        zpart[((size_t)b * NCH + c) * DQn + tid] = zs;
    }
}

// ---------------- Kernel 3: exact denom + combine + concat ----------------
// z = (Σ_c znum_c) / (S' + 1e-6 * exp(mx - 15))   — identical to reference softmax math.
__global__ __launch_bounds__(256) void final_kernel(const float* __restrict__ input_p,
                                                    const float* __restrict__ zpart,
                                                    const float* __restrict__ spart,
                                                    const float* __restrict__ mpart,
                                                    float* __restrict__ out) {
    int b = blockIdx.x, tid = threadIdx.x;
    float S = 0.f, mx = -1e30f;
#pragma unroll 8
    for (int c = 0; c < NCH; c++) {
        S += spart[b * NCH + c];
        mx = fmaxf(mx, mpart[b * NCH + c]);
    }
    float denom = S + 1e-6f * __expf(mx - 15.f);
    float inv = 1.0f / denom;
    float zs = 0.f;
#pragma unroll 8
    for (int c = 0; c < NCH; c++) zs += zpart[((size_t)b * NCH + c) * DQn + tid];
    out[(size_t)b * 512 + tid] = input_p[(size_t)b * DPn + tid];
    out[(size_t)b * 512 + 256 + tid] = zs * inv;
}

extern "C" void kernel_launch(void* const* d_in, const int* in_sizes, int n_in,
                              void* d_out, int out_size, void* d_ws, size_t ws_size,
                              hipStream_t stream) {
    const float* input_p = (const float*)d_in[0];
    // d_in[1] = mask_p (unused by reference)
    const float* input_q = (const float*)d_in[2];
    const int*   mask_q  = (const int*)d_in[3];
    const float* h_tm1   = (const float*)d_in[4];
    const float* W_p_r   = (const float*)d_in[5];
    const float* b_p_r   = (const float*)d_in[6];
    const float* W_q     = (const float*)d_in[7];
    const float* b_q     = (const float*)d_in[8];
    const float* w       = (const float*)d_in[9];
    const float* match_b = (const float*)d_in[10];
    // d_in[11] = depth (unused, layer 0)
    float* out = (float*)d_out;

    char* ws = (char*)d_ws;
    unsigned short* wqbf = (unsigned short*)ws;                   // 128 KiB
    float* base  = (float*)(ws + 131072);                         // 128 KiB
    float* zpart = (float*)(ws + 262144);                         // 128*32*256*4 = 4 MiB
    float* spart = (float*)(ws + 262144 + 4194304);               // 16 KiB
    float* mpart = (float*)(ws + 262144 + 4194304 + 16384);       // 16 KiB

    cvt_wq_kernel<<<64, 256, 0, stream>>>(W_q, wqbf);
    base_kernel<<<Bn, 256, 0, stream>>>(input_p, h_tm1, W_p_r, b_p_r, b_q, base);
    fused_kernel<<<dim3(NCH, Bn), 256, 0, stream>>>(input_q, wqbf, base, w, match_b,
                                                    mask_q, zpart, spart, mpart);
    final_kernel<<<Bn, 256, 0, stream>>>(input_p, zpart, spart, mpart, out);
}